// Round 9
// baseline (38.566 us; speedup 1.0000x reference)
//
#include <hip/hip_runtime.h>
#include <math.h>

// Problem constants: B=32, H=100, C=50, D=400, HID=400
#define B_   32
#define H_   100
#define C_   50
#define D_   400
#define HID_ 400
#define T_   7                      // d-tiles of 16 float4 (tile 6 = 4 float4)

#define NEGF (-3.4028234663852886e38f)  // finfo(float32).min

// Algebraic collapse (verified R1-R8, absmax 1.5e-5):
//   weights[b,h] = softmax_h(mask ? hist[b,h]·u : finfo.min), u = W1[D:,:]@w2
//   out[b,c,:]   = mask_cand[b,c] ? sum_h w[b,h]*hist[b,h,:] : 0
//
// Evidence ledger:
//   R4: atomic grid sync = +28us (cross-XCD coherence). Use dispatch edges.
//   R7/R8: 32-block kernels lose 4-6us (per-CU serialization). Grid >= 224.
//   R6 (best 14.7): wide grids BUT hist read twice from HBM + s_part L3
//   round-trip + k_out re-read.
// R9: K2 = 224 blocks x 1024 thr. Each block prefetches FULL hist rows into
// registers (before the u barrier), computes ALL 100 scores redundantly
// (x7 per b, L2-shared via XCD-residue mapping), softmax, then reuses the
// SAME registers for its d-tile's weighted sum — hist touched once per block,
// no scratch round-trip, single load burst per block.

__device__ __forceinline__ float dot4(float4 a, float4 b) {
    return fmaf(a.x, b.x, fmaf(a.y, b.y, fmaf(a.z, b.z, a.w * b.w)));
}

// ---- K1: u[row] = dot(W1[D+row,:], w2). One wave per row. grid=50x512 ----
__global__ __launch_bounds__(512)
void k1_u(const float* __restrict__ W1, const float* __restrict__ w2,
          float* __restrict__ u) {
    const int row  = blockIdx.x * 8 + (threadIdx.x >> 6);   // 0..399
    const int lane = threadIdx.x & 63;
    const float4* r4 = (const float4*)(W1 + (size_t)(D_ + row) * HID_);
    const float4* w4 = (const float4*)w2;
    float acc = dot4(r4[lane], w4[lane]);
    if (lane < 36)                      // 100 float4 per row = 64 + 36
        acc += dot4(r4[64 + lane], w4[64 + lane]);
    #pragma unroll
    for (int off = 32; off; off >>= 1) acc += __shfl_xor(acc, off, 64);
    if (lane == 0) u[row] = acc;
}

// ---- K2: grid = 224 (XCD-residue: 7 tiles of a b share blockIdx%8),
//      block = 1024. Redundant in-register scores + softmax + tile output ----
__global__ __launch_bounds__(1024)
void k2_fused(const float* __restrict__ hist,      // (B,H,D)
              const float* __restrict__ u,         // (D)
              const int*   __restrict__ mask_hist, // (B,H)
              const int*   __restrict__ mask_cand, // (B,C)
              float* __restrict__ out)             // (B,C,D)
{
    __shared__ float4 u4_lds[100];
    __shared__ float  s_lds[H_];
    __shared__ float  w_lds[H_];
    __shared__ float4 part_lds[16][17];  // [wave][col] +1 pad (bank-safe)
    __shared__ float4 uv4_lds[16];

    // XCD-residue decode: x = blk%8 is the (assumed) XCD; all 7 tiles of a
    // given b share x so hist[b] is fetched into one L2.
    const int x    = blockIdx.x & 7;
    const int k    = blockIdx.x >> 3;    // 0..27
    const int q    = k / 7;              // 0..3
    const int b    = x + 8 * q;          // 0..31
    const int tile = k - 7 * q;          // 0..6
    const int cols4 = (tile < 6) ? 16 : 4;   // f4 columns in this tile

    const int tid  = threadIdx.x;
    const int lane = tid & 63;
    const int wave = tid >> 6;           // 0..15
    const int l16  = tid & 15;
    const int g    = tid >> 4;           // 16-lane group 0..63

    const float4* h4 = (const float4*)(hist + (size_t)b * H_ * D_); // 100 f4/row

    // ---- u -> LDS (L3-hot from K1) ----
    if (tid < 100) u4_lds[tid] = ((const float4*)u)[tid];

    // ---- Prefetch FULL rows g and g+64 into registers (independent of u) ----
    const int row0 = g;                  // < 100
    const int row1 = g + 64;             // valid for g < 36
    const float4 z4 = make_float4(0.f, 0.f, 0.f, 0.f);
    float4 ha0[7], ha1[7];
    #pragma unroll
    for (int j = 0; j < 6; j++) ha0[j] = h4[(size_t)row0 * 100 + l16 + 16 * j];
    ha0[6] = (l16 < 4) ? h4[(size_t)row0 * 100 + 96 + l16] : z4;
    #pragma unroll
    for (int j = 0; j < 7; j++) ha1[j] = z4;
    if (row1 < H_) {
        #pragma unroll
        for (int j = 0; j < 6; j++) ha1[j] = h4[(size_t)row1 * 100 + l16 + 16 * j];
        ha1[6] = (l16 < 4) ? h4[(size_t)row1 * 100 + 96 + l16] : z4;
    }
    const int mh0 = mask_hist[b * H_ + row0];
    const int mh1 = (row1 < H_) ? mask_hist[b * H_ + row1] : 0;
    __syncthreads();                     // u4_lds ready

    // ---- Scores: 16-lane-group dot per row ----
    {
        float acc = 0.f;
        #pragma unroll
        for (int j = 0; j < 6; j++) acc += dot4(ha0[j], u4_lds[l16 + 16 * j]);
        if (l16 < 4) acc += dot4(ha0[6], u4_lds[96 + l16]);
        #pragma unroll
        for (int off = 8; off; off >>= 1) acc += __shfl_xor(acc, off, 64);
        if (l16 == 0) s_lds[row0] = mh0 ? acc : NEGF;
    }
    if (row1 < H_) {
        float acc = 0.f;
        #pragma unroll
        for (int j = 0; j < 6; j++) acc += dot4(ha1[j], u4_lds[l16 + 16 * j]);
        if (l16 < 4) acc += dot4(ha1[6], u4_lds[96 + l16]);
        #pragma unroll
        for (int off = 8; off; off >>= 1) acc += __shfl_xor(acc, off, 64);
        if (l16 == 0) s_lds[row1] = mh1 ? acc : NEGF;
    }
    __syncthreads();

    // ---- Softmax over s_lds[0..99] (wave 0 publishes weights) ----
    if (wave == 0) {
        const float s0 = s_lds[lane];
        const float s1 = (lane < 36) ? s_lds[64 + lane] : -INFINITY;
        float m = fmaxf(s0, s1);
        #pragma unroll
        for (int off = 32; off; off >>= 1) m = fmaxf(m, __shfl_xor(m, off, 64));
        const float e0 = expf(s0 - m);
        const float e1 = (lane < 36) ? expf(s1 - m) : 0.f;
        float ps = e0 + e1;
        #pragma unroll
        for (int off = 32; off; off >>= 1) ps += __shfl_xor(ps, off, 64);
        const float inv = 1.f / ps;
        w_lds[lane] = e0 * inv;
        if (lane < 36) w_lds[64 + lane] = e1 * inv;
    }
    __syncthreads();

    // ---- V: this tile's weighted-sum from the ALREADY-HELD registers ----
    // Lane holds column quadrant (tile, l16) of its rows: ha*[tile].
    float4 pv = z4;
    {
        const float w0 = w_lds[row0];
        pv.x = w0 * ha0[tile].x; pv.y = w0 * ha0[tile].y;
        pv.z = w0 * ha0[tile].z; pv.w = w0 * ha0[tile].w;
        if (row1 < H_) {
            const float w1 = w_lds[row1];
            pv.x = fmaf(w1, ha1[tile].x, pv.x);
            pv.y = fmaf(w1, ha1[tile].y, pv.y);
            pv.z = fmaf(w1, ha1[tile].z, pv.z);
            pv.w = fmaf(w1, ha1[tile].w, pv.w);
        }
    }
    // reduce across the 4 groups of each wave (lanes 16,32 apart)
    #pragma unroll
    for (int off = 16; off <= 32; off <<= 1) {
        pv.x += __shfl_xor(pv.x, off, 64);
        pv.y += __shfl_xor(pv.y, off, 64);
        pv.z += __shfl_xor(pv.z, off, 64);
        pv.w += __shfl_xor(pv.w, off, 64);
    }
    if (lane < 16) part_lds[wave][lane] = pv;   // wave-partial per column
    __syncthreads();
    if (tid < 16) {                              // 16 cols x 16 wave-partials
        float4 s = z4;
        #pragma unroll
        for (int i = 0; i < 16; i++) {
            float4 p = part_lds[i][tid];
            s.x += p.x; s.y += p.y; s.z += p.z; s.w += p.w;
        }
        uv4_lds[tid] = s;
    }
    __syncthreads();

    // ---- O: out[b, c, tile] = mask_cand[b,c] ? uv : 0 ----
    const int total = C_ * cols4;                // 800 or 200 f4
    const int* mc = mask_cand + b * C_;
    float4* outb = (float4*)(out + (size_t)b * C_ * D_);
    if (tid < total) {
        const int c = tid / cols4;
        const int f = tid - c * cols4;
        outb[(size_t)c * 100 + tile * 16 + f] = mc[c] ? uv4_lds[f] : z4;
    }
}

extern "C" void kernel_launch(void* const* d_in, const int* in_sizes, int n_in,
                              void* d_out, int out_size, void* d_ws, size_t ws_size,
                              hipStream_t stream) {
    // inputs: 0 hist(B,H,D) f32, 1 cand [unused], 2 mask_hist(B,H) i32,
    //         3 mask_cand(B,C) i32, 4 W1(2D,HID) f32, 5 b1 [unused],
    //         6 w2(HID) f32, 7 b2 [unused]
    const float* hist      = (const float*)d_in[0];
    const int*   mask_hist = (const int*)d_in[2];
    const int*   mask_cand = (const int*)d_in[3];
    const float* W1        = (const float*)d_in[4];
    const float* w2        = (const float*)d_in[6];
    float* out = (float*)d_out;

    float* u = (float*)d_ws;    // 400 floats scratch

    k1_u    <<<D_ / 8,  512,  0, stream>>>(W1, w2, u);
    k2_fused<<<B_ * T_, 1024, 0, stream>>>(hist, u, mask_hist, mask_cand, out);
}

// Round 10
// 14.586 us; speedup vs baseline: 2.6440x; 2.6440x over previous
//
#include <hip/hip_runtime.h>
#include <math.h>

// Problem constants: B=32, H=100, C=50, D=400, HID=400
#define B_   32
#define H_   100
#define C_   50
#define D_   400
#define HID_ 400
#define ROWS (B_ * H_)              // 3200 score rows
#define T_   7                      // d-tiles of 64 floats (tile 6 = 16 floats)
#define SPLD 8                      // s_part row stride (7 partials + pad)

#define NEGF (-3.4028234663852886e38f)  // finfo(float32).min

// Algebraic collapse (verified R1-R9, absmax 1.5e-5):
//   weights[b,h] = softmax_h(mask ? hist[b,h]·u : finfo.min), u = W1[D:,:]@w2
//   out[b,c,:]   = mask_cand[b,c] ? sum_h w[b,h]*hist[b,h,:] : 0
//
// Evidence ledger:
//   R4: atomic grid sync +28us (cross-XCD coherence). Use dispatch edges.
//   R7/R8: 32-block kernels lose 4-6us (per-CU serialization). Grid >= 224.
//   R9: full-row redundancy = 35.8MB traffic, +24us. Replicate only u-slices.
//   R6 (best 14.7): k_scores good; k_out used a MISMATCHED block->XCD mapping
//   (b*7+t vs t*32+r), so its hist re-read missed the producer XCD's L2.
// R10: k_out decode matched to k_scores (t*32+b -> residue b%8 for BOTH
// kernels' b-blocks). hist tile + s_part rows for b stay on XCD b%8: the
// 5.1MB re-read becomes same-XCD L2 hits. k_out reads only its 25.6KB tile,
// prefetched to registers above the softmax barrier.

__device__ __forceinline__ float dot4(float4 a, float4 b) {
    return fmaf(a.x, b.x, fmaf(a.y, b.y, fmaf(a.z, b.z, a.w * b.w)));
}

// ---- K_scores: grid = 7*32 = 224 blocks (t = blk>>5, r = blk&31), 512 thr.
//      Verbatim from R6 (verified 14.7us component). Block (t,r): computes
//      u-slice for d in [64t, 64t+dt), then s_part[row][t] for rows
//      [100r, 100r+100). ----
__global__ __launch_bounds__(512)
void k_scores(const float* __restrict__ hist,   // (3200, 400)
              const float* __restrict__ W1,     // (800, 400)
              const float* __restrict__ w2,     // (400)
              float* __restrict__ s_part) {     // (3200, 8)
    __shared__ float u_lds[64];

    const int t    = blockIdx.x >> 5;           // 0..6
    const int r    = blockIdx.x & 31;           // 0..31
    const int d0   = t * 64;
    const int dt   = (t < 6) ? 64 : 16;
    const int dt4  = dt >> 2;                   // 16 or 4
    const int tid  = threadIdx.x;
    const int lane = tid & 63;
    const int wave = tid >> 6;
    const int l16  = lane & 15;
    const int sub  = lane >> 4;                 // 0..3
    const int g    = tid >> 4;                  // 16-lane group id, 0..31

    // ---- Hoisted hist loads (independent of u): 4 rows per lane-group ----
    const float4* h4 = (const float4*)hist;     // row stride 100 float4
    const bool cload = (l16 < dt4);
    float4 ha[4];
    int   rown[4];
    #pragma unroll
    for (int p = 0; p < 4; p++) {
        const int rl = p * 32 + wave * 4 + sub; // 0..127
        rown[p] = r * 100 + rl;
        ha[p] = (rl < 100 && cload)
              ? h4[(size_t)rown[p] * 100 + t * 16 + l16]
              : make_float4(0.f, 0.f, 0.f, 0.f);
    }

    // ---- Phase 1: u[i] = dot(W1[D+d0+i,:], w2), one row per 16-lane group ----
    const float4* w24 = (const float4*)w2;      // 100 float4
    #pragma unroll 2
    for (int i = g; i < dt; i += 32) {
        const float4* row4 = (const float4*)(W1 + (size_t)(D_ + d0 + i) * HID_);
        float acc = 0.f;
        #pragma unroll
        for (int k = 0; k < 6; k++)             // l16 + 16k <= 95 < 100 always
            acc += dot4(row4[l16 + 16 * k], w24[l16 + 16 * k]);
        if (l16 < 4)                            // tail: 96..99
            acc += dot4(row4[96 + l16], w24[96 + l16]);
        #pragma unroll
        for (int off = 8; off; off >>= 1)
            acc += __shfl_xor(acc, off, 64);
        if (l16 == 0) u_lds[i] = acc;
    }
    __syncthreads();

    // ---- Phase 2: partial scores with the prefetched hist values ----
    const float4 uu = cload ? ((const float4*)u_lds)[l16]
                            : make_float4(0.f, 0.f, 0.f, 0.f);
    #pragma unroll
    for (int p = 0; p < 4; p++) {
        const int rl = p * 32 + wave * 4 + sub;
        float acc = dot4(ha[p], uu);
        #pragma unroll
        for (int off = 8; off; off >>= 1)       // reduce within 16-lane group
            acc += __shfl_xor(acc, off, 64);
        if (rl < 100 && l16 == 0)
            s_part[(size_t)rown[p] * SPLD + t] = acc;
    }
}

// ---- K_out: grid = 224 blocks, decode MATCHED to k_scores:
//      t = blk>>5, b = blk&31 (same XCD residue b%8 as producers), 256 thr.
//      Reads only hist[b][:, tile] (25.6KB, same-XCD L2-hot). ----
__global__ __launch_bounds__(256)
void k_out(const float* __restrict__ hist, const float* __restrict__ s_part,
           const int* __restrict__ mask_hist, const int* __restrict__ mask_cand,
           float* __restrict__ out) {
    __shared__ float  s_lds[H_];
    __shared__ float  w_lds[H_];
    __shared__ float4 part_lds[16][17];   // [hgroup][col4], padded
    __shared__ float4 uv4_lds[16];

    const int t     = blockIdx.x >> 5;    // 0..6
    const int b     = blockIdx.x & 31;    // 0..31
    const int cols4 = (t < 6) ? 16 : 4;   // f4 columns in this tile
    const int tid   = threadIdx.x;
    const int lane  = tid & 63;
    const int wave  = tid >> 6;
    const int l16   = tid & 15;
    const int g     = tid >> 4;           // h-group 0..15

    const float4 z4 = make_float4(0.f, 0.f, 0.f, 0.f);
    const float4* h4 = (const float4*)(hist + (size_t)b * H_ * D_); // 100 f4/row

    // ---- Prefetch tile rows to registers (independent of softmax):
    //      thread (g,l16) holds hist[b][g+16k][t*16+l16], k=0..6 ----
    float4 rv[7];
    const bool cv = (l16 < cols4);
    #pragma unroll
    for (int k = 0; k < 7; k++) {
        const int h = g + 16 * k;
        rv[k] = (h < H_ && cv) ? h4[(size_t)h * 100 + t * 16 + l16] : z4;
    }

    // ---- s_part reduce (fixed order, deterministic) + mask ----
    if (tid < H_) {
        const int row = b * H_ + tid;
        const float4* sp4 = (const float4*)(s_part + (size_t)row * SPLD);
        float4 a = sp4[0], c = sp4[1];    // slots 0..6 valid, 7 = pad
        float sum = ((a.x + a.y) + (a.z + a.w)) + ((c.x + c.y) + c.z);
        s_lds[tid] = mask_hist[row] ? sum : NEGF;
    }
    __syncthreads();

    // ---- softmax over s_lds[0..99], redundant per wave ----
    {
        const float s0 = s_lds[lane];
        const float s1 = (lane < 36) ? s_lds[64 + lane] : -INFINITY;
        float m = fmaxf(s0, s1);
        #pragma unroll
        for (int off = 32; off; off >>= 1) m = fmaxf(m, __shfl_xor(m, off, 64));
        const float e0 = expf(s0 - m);
        const float e1 = (lane < 36) ? expf(s1 - m) : 0.f;
        float ps = e0 + e1;
        #pragma unroll
        for (int off = 32; off; off >>= 1) ps += __shfl_xor(ps, off, 64);
        const float inv = 1.f / ps;
        if (wave == 0) {
            w_lds[lane] = e0 * inv;
            if (lane < 36) w_lds[64 + lane] = e1 * inv;
        }
    }
    __syncthreads();

    // ---- V: acc = sum_k w[g+16k] * rv[k]; reduce over 16 h-groups ----
    float4 acc = z4;
    #pragma unroll
    for (int k = 0; k < 7; k++) {
        const int h = g + 16 * k;
        if (h < H_) {
            const float w = w_lds[h];
            acc.x = fmaf(w, rv[k].x, acc.x);
            acc.y = fmaf(w, rv[k].y, acc.y);
            acc.z = fmaf(w, rv[k].z, acc.z);
            acc.w = fmaf(w, rv[k].w, acc.w);
        }
    }
    part_lds[g][l16] = acc;
    __syncthreads();
    if (tid < 16) {                       // col tid: sum 16 group-partials
        float4 s = z4;
        #pragma unroll
        for (int i = 0; i < 16; i++) {
            float4 p = part_lds[i][tid];
            s.x += p.x; s.y += p.y; s.z += p.z; s.w += p.w;
        }
        uv4_lds[tid] = s;
    }
    __syncthreads();

    // ---- O: out[b, c, tile] = mask_cand[b,c] ? uv : 0 ----
    const int* mc = mask_cand + b * C_;
    float4* outb = (float4*)(out + (size_t)b * C_ * D_);   // 100 f4/row
    const int f = tid & 15;               // col4 within tile
    #pragma unroll
    for (int i = 0; i < 4; i++) {
        const int c = (tid >> 4) + 16 * i;           // 0..63
        if (c < C_ && f < cols4)
            outb[(size_t)c * 100 + t * 16 + f] = mc[c] ? uv4_lds[f] : z4;
    }
}

extern "C" void kernel_launch(void* const* d_in, const int* in_sizes, int n_in,
                              void* d_out, int out_size, void* d_ws, size_t ws_size,
                              hipStream_t stream) {
    // inputs: 0 hist(B,H,D) f32, 1 cand [unused], 2 mask_hist(B,H) i32,
    //         3 mask_cand(B,C) i32, 4 W1(2D,HID) f32, 5 b1 [unused],
    //         6 w2(HID) f32, 7 b2 [unused]
    const float* hist      = (const float*)d_in[0];
    const int*   mask_hist = (const int*)d_in[2];
    const int*   mask_cand = (const int*)d_in[3];
    const float* W1        = (const float*)d_in[4];
    const float* w2        = (const float*)d_in[6];
    float* out = (float*)d_out;

    float* s_part = (float*)d_ws;   // 3200*8 floats = 102.4 KB scratch

    k_scores<<<T_ * 32, 512, 0, stream>>>(hist, W1, w2, s_part);
    k_out   <<<T_ * 32, 256, 0, stream>>>(hist, s_part, mask_hist, mask_cand, out);
}